// Round 19
// baseline (527.512 us; speedup 1.0000x reference)
//
#include <hip/hip_runtime.h>
#include <stdint.h>

typedef unsigned short ushort_t;
typedef __attribute__((ext_vector_type(8))) short bf16x8;
typedef __attribute__((ext_vector_type(4))) float f32x4;
typedef __attribute__((ext_vector_type(8))) unsigned short u16x8;

__device__ __forceinline__ ushort_t f2bf(float f) {
  union { float f; unsigned u; } v; v.f = f;
  unsigned r = v.u + 0x7fffu + ((v.u >> 16) & 1u);
  return (ushort_t)(r >> 16);
}
__device__ __forceinline__ float bf2f(ushort_t u) {
  union { unsigned u; float f; } v; v.u = ((unsigned)u) << 16;
  return v.f;
}

__device__ __forceinline__ void gload_lds16(const void* g, void* l) {
  __builtin_amdgcn_global_load_lds(
      (const __attribute__((address_space(1))) void*)g,
      (__attribute__((address_space(3))) void*)l, 16, 0, 0);
}

// ---------------- fused prep: weight transpose+cast | time-shift mix -------
// R15-verified (83us; ~3.4 TB/s, structural BW limit for this pattern).
struct PrepArgs {
  const float* W[5];
  ushort_t* Wt[5];
  const float* Hd;
  const float* mr; const float* mk; const float* mv; const float* mg;
  ushort_t* xr; ushort_t* xk; ushort_t* xv; ushort_t* xg;
};

__global__ __launch_bounds__(256) void prep(PrepArgs a, int n, int Mrows, int Tt) {
  const int bid = blockIdx.x;
  const int tid = threadIdx.x;
  if (bid < 5120) {
    // ---- weight transpose+cast, 64x64 tile ----
    const int z = bid >> 10;
    const int tt = bid & 1023;
    const int bx = tt & 31, by = tt >> 5;
    const float* __restrict__ W = a.W[z];
    ushort_t* __restrict__ Wt = a.Wt[z];
    __shared__ float tile[64][65];
    const int cx = tid & 15, ry = tid >> 4;  // load: 16 col-groups x 16 rows
#pragma unroll
    for (int r = 0; r < 4; ++r) {
      const int row = ry + 16 * r;
      f32x4 v = *(const f32x4*)&W[(size_t)(by * 64 + row) * n + bx * 64 + cx * 4];
      tile[row][cx * 4 + 0] = v[0];
      tile[row][cx * 4 + 1] = v[1];
      tile[row][cx * 4 + 2] = v[2];
      tile[row][cx * 4 + 3] = v[3];
    }
    __syncthreads();
    const int gx = tid & 7, oy = tid >> 3;  // write: 8 col-groups x 32 rows
#pragma unroll
    for (int r = 0; r < 2; ++r) {
      const int orow = oy + 32 * r;
      u16x8 o;
#pragma unroll
      for (int e = 0; e < 8; ++e) o[e] = f2bf(tile[gx * 8 + e][orow]);
      *(u16x8*)&Wt[(size_t)(bx * 64 + orow) * n + by * 64 + gx * 8] = o;
    }
    return;
  }
  // ---- mix path: one block per row ----
  const int Cc = n;
  const int row = bid - 5120;  // 0..Mrows-1
  const int t = row & (Tt - 1);
  const float* __restrict__ Hd = a.Hd;
  const size_t e = (size_t)row * Cc + tid * 8;
  const int c = tid * 8;
  f32x4 h0 = *(const f32x4*)&Hd[e];
  f32x4 h1 = *(const f32x4*)&Hd[e + 4];
  f32x4 sA = {0.f, 0.f, 0.f, 0.f}, sB = {0.f, 0.f, 0.f, 0.f};
  if (t != 0) {
    sA = *(const f32x4*)&Hd[e - Cc];
    sB = *(const f32x4*)&Hd[e - Cc + 4];
  }
  f32x4 mA[4], mB[4];
  mA[0] = *(const f32x4*)&a.mr[c]; mB[0] = *(const f32x4*)&a.mr[c + 4];
  mA[1] = *(const f32x4*)&a.mk[c]; mB[1] = *(const f32x4*)&a.mk[c + 4];
  mA[2] = *(const f32x4*)&a.mv[c]; mB[2] = *(const f32x4*)&a.mv[c + 4];
  mA[3] = *(const f32x4*)&a.mg[c]; mB[3] = *(const f32x4*)&a.mg[c + 4];
  u16x8 o[4];
#pragma unroll
  for (int w = 0; w < 4; ++w) {
#pragma unroll
    for (int q = 0; q < 4; ++q) {
      o[w][q]     = f2bf(sA[q] + (h0[q] - sA[q]) * mA[w][q]);
      o[w][q + 4] = f2bf(sB[q] + (h1[q] - sB[q]) * mB[w][q]);
    }
  }
  *(u16x8*)&a.xr[e] = o[0];
  *(u16x8*)&a.xk[e] = o[1];
  *(u16x8*)&a.xv[e] = o[2];
  *(u16x8*)&a.xg[e] = o[3];
}

// ======== 256x256 bf16 GEMM, counted-vmcnt pipeline, XOR-swizzled LDS ========
// R15/R18-verified math + fences, extended with the m201-style FULL phase
// bracket: each phase is now {reads -> barrier -> [stage] -> lgkmcnt(0) ->
// setprio(1) -> 16 MFMA -> setprio(0) -> barrier}.  The fence set strictly
// CONTAINS the R15-verified set (all original barriers remain, uniform
// control flow) -> no new hazard windows.  Mechanism being tested: the
// trailing barriers create the per-phase wave role-split that setprio needs
// to arbitrate (T5 is +21-39% with the full bracket, ~0% without).
struct GemmArgs {
  const ushort_t* A[4];
  const ushort_t* Bt[4];
  void* C[4];
};

__device__ __forceinline__ void stage_mat(const ushort_t* __restrict__ base,
                                          int K, int voff, char* ldsmat,
                                          int tid) {
#pragma unroll
  for (int hf = 0; hf < 2; ++hf)
#pragma unroll
    for (int s = 0; s < 2; ++s)
      gload_lds16(base + (size_t)(hf * 128 + s * 64) * K + voff,
                  ldsmat + hf * 16384 + s * 8192 + tid * 16);
}

template <int BF16OUT>
__global__ __launch_bounds__(512, 1) void gemm256(GemmArgs args, int M, int N, int K) {
  extern __shared__ char lds[];  // 131072 bytes: 2 bufs x (A 32KB | B 32KB)
  const int z = blockIdx.z;
  const ushort_t* __restrict__ A = args.A[z];
  const ushort_t* __restrict__ Bt = args.Bt[z];

  const int tid = threadIdx.x;
  const int lane = tid & 63, w = tid >> 6;
  const int wm = w >> 2, wn = w & 3;       // 2 x 4 waves
  const int r16 = lane & 15, kb = lane >> 4;

  // XCD-aware bijective swizzle (nwg % 8 == 0 for our shapes)
  const int nbx = N >> 8;
  const int nwg = nbx * (M >> 8);
  const int orig = blockIdx.y * nbx + blockIdx.x;
  const int wid = (orig & 7) * (nwg >> 3) + (orig >> 3);
  const int bm0 = (wid / nbx) << 8;
  const int bn0 = (wid % nbx) << 8;

  // Per-thread staging source offset (elements), shared by all 8 gloads.
  const int trow = tid >> 3;  // 0..63
  const int voff = trow * K + (((((tid & 7) * 16) ^ ((trow & 7) << 4))) >> 1);
  const ushort_t* __restrict__ Abase = A + (size_t)bm0 * K;
  const ushort_t* __restrict__ Bbase = Bt + (size_t)bn0 * K;

  // Swizzled LDS byte offsets (ks=0 only; ks=1 = off ^ 64, carry-free since
  // low 7 bits of the unswizzled offset are kb*16 <= 48).
  int aoff[8], boff[4];
#pragma unroll
  for (int mi = 0; mi < 8; ++mi) {
    const int d = (mi * 16 + r16) * 128 + kb * 16;
    aoff[mi] = wm * 16384 + (d ^ (((d >> 7) & 7) << 4));
  }
#pragma unroll
  for (int ni = 0; ni < 4; ++ni) {
    const int d = ((wn & 1) * 64 + ni * 16 + r16) * 128 + kb * 16;
    boff[ni] = 32768 + (wn >> 1) * 16384 + (d ^ (((d >> 7) & 7) << 4));
  }

  f32x4 acc[8][4] = {};
  const int NT = K >> 6;

  // prologue: tiles 0,1 -> bufs 0,1; wait tile0 (8 of 16 loads), tile1 flies
  stage_mat(Abase, K, voff, lds, tid);
  stage_mat(Bbase, K, voff, lds + 32768, tid);
  stage_mat(Abase + 64, K, voff, lds + 65536, tid);
  stage_mat(Bbase + 64, K, voff, lds + 65536 + 32768, tid);
  asm volatile("s_waitcnt vmcnt(8)" ::: "memory");
  asm volatile("s_barrier" ::: "memory");

  for (int t = 0; t < NT; ++t) {
    const int cur = t & 1;
    char* cbase = lds + cur * 65536;
    bf16x8 ah[4][2], bq[4][2];

    // ---- ph0: read A-half0 + B-quad0 | barrier | lgkm0 | MFMA | barrier ----
#pragma unroll
    for (int m = 0; m < 4; ++m) {
      ah[m][0] = *(const bf16x8*)(cbase + aoff[m]);
      ah[m][1] = *(const bf16x8*)(cbase + (aoff[m] ^ 64));
    }
#pragma unroll
    for (int n = 0; n < 2; ++n) {
      bq[n][0] = *(const bf16x8*)(cbase + boff[n]);
      bq[n][1] = *(const bf16x8*)(cbase + (boff[n] ^ 64));
    }
    asm volatile("s_barrier" ::: "memory");
    asm volatile("s_waitcnt lgkmcnt(0)" ::: "memory");
    __builtin_amdgcn_s_setprio(1);
#pragma unroll
    for (int m = 0; m < 4; ++m)
#pragma unroll
      for (int n = 0; n < 2; ++n)
#pragma unroll
        for (int ks = 0; ks < 2; ++ks)
          acc[m][n] = __builtin_amdgcn_mfma_f32_16x16x32_bf16(
              ah[m][ks], bq[n][ks], acc[m][n], 0, 0, 0);
    __builtin_amdgcn_s_setprio(0);
    asm volatile("s_barrier" ::: "memory");

    // ---- ph1: read B-quad1 | barrier | lgkm0 | MFMA | barrier ----
#pragma unroll
    for (int n = 2; n < 4; ++n) {
      bq[n][0] = *(const bf16x8*)(cbase + boff[n]);
      bq[n][1] = *(const bf16x8*)(cbase + (boff[n] ^ 64));
    }
    asm volatile("s_barrier" ::: "memory");
    asm volatile("s_waitcnt lgkmcnt(0)" ::: "memory");
    __builtin_amdgcn_s_setprio(1);
#pragma unroll
    for (int m = 0; m < 4; ++m)
#pragma unroll
      for (int n = 2; n < 4; ++n)
#pragma unroll
        for (int ks = 0; ks < 2; ++ks)
          acc[m][n] = __builtin_amdgcn_mfma_f32_16x16x32_bf16(
              ah[m][ks], bq[n][ks], acc[m][n], 0, 0, 0);
    __builtin_amdgcn_s_setprio(0);
    asm volatile("s_barrier" ::: "memory");

    // ---- ph2: read A-half1 | barrier (WAR: all reads of buf[cur] issued) |
    //      stage t+2 A-half | lgkm0 | MFMA | barrier ----
#pragma unroll
    for (int m = 0; m < 4; ++m) {
      ah[m][0] = *(const bf16x8*)(cbase + aoff[4 + m]);
      ah[m][1] = *(const bf16x8*)(cbase + (aoff[4 + m] ^ 64));
    }
    asm volatile("s_barrier" ::: "memory");
    if (t + 2 < NT)
      stage_mat(Abase + (t + 2) * 64, K, voff, cbase, tid);
    asm volatile("s_waitcnt lgkmcnt(0)" ::: "memory");
    __builtin_amdgcn_s_setprio(1);
#pragma unroll
    for (int m = 0; m < 4; ++m)
#pragma unroll
      for (int n = 0; n < 2; ++n)
#pragma unroll
        for (int ks = 0; ks < 2; ++ks)
          acc[4 + m][n] = __builtin_amdgcn_mfma_f32_16x16x32_bf16(
              ah[m][ks], bq[n][ks], acc[4 + m][n], 0, 0, 0);
    __builtin_amdgcn_s_setprio(0);
    asm volatile("s_barrier" ::: "memory");

    // ---- ph3: stage t+2 B-half | vmcnt(8|0)+barrier (RAW) | MFMA ----
    if (t + 2 < NT)
      stage_mat(Bbase + (t + 2) * 64, K, voff, cbase + 32768, tid);
    if (t + 1 < NT) {
      if (t + 2 < NT)
        asm volatile("s_waitcnt vmcnt(8)" ::: "memory");  // t+1 landed; t+2 flies
      else
        asm volatile("s_waitcnt vmcnt(0)" ::: "memory");  // tail drain
      asm volatile("s_barrier" ::: "memory");
    }
    __builtin_amdgcn_s_setprio(1);
#pragma unroll
    for (int m = 0; m < 4; ++m)
#pragma unroll
      for (int n = 2; n < 4; ++n)
#pragma unroll
        for (int ks = 0; ks < 2; ++ks)
          acc[4 + m][n] = __builtin_amdgcn_mfma_f32_16x16x32_bf16(
              ah[m][ks], bq[n][ks], acc[4 + m][n], 0, 0, 0);
    __builtin_amdgcn_s_setprio(0);
  }

  const int row0 = bm0 + wm * 128 + kb * 4;
  const int col0 = bn0 + wn * 64 + r16;
#pragma unroll
  for (int mi = 0; mi < 8; ++mi)
#pragma unroll
    for (int ni = 0; ni < 4; ++ni) {
      f32x4 v = acc[mi][ni];
      const int row = row0 + mi * 16;
      const int col = col0 + ni * 16;
#pragma unroll
      for (int rr = 0; rr < 4; ++rr) {
        if (BF16OUT)
          ((ushort_t*)args.C[z])[(size_t)(row + rr) * N + col] = f2bf(v[rr]);
        else
          ((float*)args.C[z])[(size_t)(row + rr) * N + col] = v[rr];
      }
    }
}

// ======== Phase A: intra-chunk WKV via chunked-matmul (MFMA) ========
// R14-verified: 1024 threads / 16 waves, swizzled Vt/Kt, power tables.
__global__ __launch_bounds__(1024, 1) void wkv_chunk(
    const ushort_t* __restrict__ Rm, const ushort_t* __restrict__ Km,
    const ushort_t* __restrict__ Vm, const float* __restrict__ td,
    const float* __restrict__ tf,
    float* __restrict__ Oatt, float* __restrict__ chunkA,
    int Tt, int Hh, int NC, int Lc) {
  extern __shared__ char smem[];
  ushort_t* Rs  = (ushort_t*)(smem + 0);       // [128][72] raw r
  ushort_t* Ks  = (ushort_t*)(smem + 18432);   // [128][72] raw k (diag only)
  ushort_t* Ks2 = (ushort_t*)(smem + 36864);   // [128][72] k*w^{15-s16}
  ushort_t* Vt  = (ushort_t*)(smem + 55296);   // [64][136] v transp (swizzled)
  ushort_t* Kt  = (ushort_t*)(smem + 72704);   // [64][136] k*w^{127-s} (swz)
  ushort_t* At  = (ushort_t*)(smem + 90112);   // [128][136]
  float* wp   = (float*)(smem + 124928);       // [16][68] w^d
  float* w16p = (float*)(smem + 129280);       // [8][68]  w^{16q}
  float* u_   = (float*)(smem + 131456);       // [64]

  const int blk = blockIdx.x;
  const int bh = blk / NC, c = blk % NC;
  const int b = bh / Hh, h = bh % Hh;
  const int tid = threadIdx.x;
  const int lane = tid & 63, w = tid >> 6;       // 16 waves
  const int r16 = lane & 15, g = lane >> 4;      // frag coords
  const int Cc = Hh * 64;
  const size_t base = ((size_t)b * Tt + (size_t)c * Lc) * Cc + h * 64;

  // ---- (1) global loads to registers (latency hides under table fill) ----
  const int srow = tid >> 3;            // 0..127
  const int scol = (tid & 7) * 8;       // 0,8,...,56
  const size_t gb = base + (size_t)srow * Cc + scol;
  u16x8 r0 = *(const u16x8*)&Rm[gb];
  u16x8 k0 = *(const u16x8*)&Km[gb];
  u16x8 v0 = *(const u16x8*)&Vm[gb];

  // ---- (2) power tables ----
  if (tid < 64) {
    const float ev = expf(td[h * 64 + tid]);
    const float wv = expf(-ev);
    u_[tid] = tf[h * 64 + tid];
    float p = 1.f;
#pragma unroll
    for (int d = 0; d < 16; ++d) { wp[d * 68 + tid] = p; p *= wv; }
    float pq = 1.f;  // p == w^16 now
#pragma unroll
    for (int q = 0; q < 8; ++q) { w16p[q * 68 + tid] = pq; pq *= p; }
  }
  __syncthreads();

  // ---- (3) LDS writes (raw + pre-scaled) + zero At ----
  {
    *(u16x8*)&Rs[srow * 72 + scol] = r0;
    *(u16x8*)&Ks[srow * 72 + scol] = k0;
    const int s16 = srow & 15, shi = srow >> 4;
    const float* fa = &wp[(15 - s16) * 68 + scol];   // w^{15-s16}[i]
    const float* gq = &w16p[(7 - shi) * 68 + scol];  // w^{16(7-shi)}[i]
    u16x8 a2;
#pragma unroll
    for (int e = 0; e < 8; ++e) a2[e] = f2bf(bf2f(k0[e]) * fa[e]);
    *(u16x8*)&Ks2[srow * 72 + scol] = a2;
    // Vt/Kt channel-row keyed swizzle: col' = srow ^ key.  key uniform per
    // instruction: (scol+e)>>4 == scol>>4 for e<8 (scol multiple of 8).
    const int key = ((scol >> 4) & 3) << 4;
    const int sc = srow ^ key;
#pragma unroll
    for (int e = 0; e < 8; ++e) {
      Vt[(scol + e) * 136 + sc] = v0[e];
      Kt[(scol + e) * 136 + sc] = f2bf(bf2f(k0[e]) * fa[e] * gq[e]);
    }
    const u16x8 z = {};
    for (int o = tid; o < (128 * 136) / 8; o += 1024) *(u16x8*)&At[o * 8] = z;
  }
  __syncthreads();

  // ---- Phase A: 28 off-diagonal tiles via MFMA (no exp2f) ----
  for (int p = w; p < 28; p += 16) {
    int tau = 1, cum = 0;
    while (cum + tau <= p) { cum += tau; ++tau; }
    const int sig = p - cum;
    const float* wr  = &wp[r16 * 68];                 // w^{t16}[i]
    const float* w16 = &w16p[(tau - sig - 1) * 68];   // w^{16(dcls-1)}[i]
    f32x4 acc = {0.f, 0.f, 0.f, 0.f};
#pragma unroll
    for (int ks = 0; ks < 2; ++ks) {
      const int ib = ks * 32 + g * 8;
      u16x8 rv = *(const u16x8*)&Rs[(tau * 16 + r16) * 72 + ib];
      bf16x8 kv = *(const bf16x8*)&Ks2[(sig * 16 + r16) * 72 + ib];
      f32x4 wa = *(const f32x4*)&wr[ib];
      f32x4 wb = *(const f32x4*)&wr[ib + 4];
      f32x4 sa = *(const f32x4*)&w16[ib];
      f32x4 sb = *(const f32x4*)&w16[ib + 4];
      union { bf16x8 v; ushort_t s[8]; } af;
#pragma unroll
      for (int e = 0; e < 4; ++e) {
        af.s[e]     = f2bf(bf2f(rv[e]) * (wa[e] * sa[e]));
        af.s[e + 4] = f2bf(bf2f(rv[e + 4]) * (wb[e] * sb[e]));
      }
      acc = __builtin_amdgcn_mfma_f32_16x16x32_bf16(af.v, kv, acc, 0, 0, 0);
    }
#pragma unroll
    for (int r = 0; r < 4; ++r)
      At[(tau * 16 + g * 4 + r) * 136 + sig * 16 + r16] = f2bf(acc[r]);
  }

  // ---- Phase B: 8 diagonal tiles entry-wise (raw Rs/Ks, unchanged) ----
  for (int rr = 0; rr < 2; ++rr) {
    const int eid = tid + rr * 1024;
    if (eid >= 1088) break;
    const int tile = eid / 136;
    const int e2 = eid % 136;
    int t = 0, cum = 0;
    while (cum + t + 1 <= e2) { cum += t + 1; ++t; }
    const int s = e2 - cum;
    const ushort_t* rrow = &Rs[(tile * 16 + t) * 72];
    const ushort_t* krow = &Ks[(tile * 16 + s) * 72];
    const float* frow = (s < t) ? &wp[(t - s - 1) * 68] : u_;
    float acc = 0.f;
#pragma unroll
    for (int i0 = 0; i0 < 64; i0 += 8) {
      u16x8 rv = *(const u16x8*)&rrow[i0];
      u16x8 kv = *(const u16x8*)&krow[i0];
      f32x4 f0 = *(const f32x4*)&frow[i0];
      f32x4 f1 = *(const f32x4*)&frow[i0 + 4];
#pragma unroll
      for (int e = 0; e < 4; ++e) {
        acc = fmaf(bf2f(rv[e]), bf2f(kv[e]) * f0[e], acc);
        acc = fmaf(bf2f(rv[e + 4]), bf2f(kv[e + 4]) * f1[e], acc);
      }
    }
    At[(tile * 16 + t) * 136 + tile * 16 + s] = f2bf(acc);
  }
  __syncthreads();

  // ---- Phase C: out = A @ V, balanced: wave w -> units {w, 31-w}
  //      (unit u: tt = u>>2, jt = u&3); 5 MFMA per wave ----
#pragma unroll
  for (int half = 0; half < 2; ++half) {
    const int u = half ? (31 - w) : w;
    const int tt = u >> 2, jt = u & 3;
    const int nk = (tt + 2) >> 1;  // ceil((tt+1)/2) k-steps of 32
    const int vk = jt << 4;        // Vt read key: (jt*16+r16)>>4 == jt
    f32x4 acc = {0.f, 0.f, 0.f, 0.f};
    for (int kk = 0; kk < nk; ++kk) {
      bf16x8 af = *(const bf16x8*)&At[(tt * 16 + r16) * 136 + kk * 32 + g * 8];
      bf16x8 bv = *(const bf16x8*)&Vt[(jt * 16 + r16) * 136 +
                                      ((kk * 32 + g * 8) ^ vk)];
      acc = __builtin_amdgcn_mfma_f32_16x16x32_bf16(af, bv, acc, 0, 0, 0);
    }
#pragma unroll
    for (int r = 0; r < 4; ++r)
      Oatt[base + (size_t)(tt * 16 + g * 4 + r) * Cc + jt * 16 + r16] = acc[r];
  }

  // ---- Phase D: chunkA = Kt(pre-scaled) @ V -- 1 tile/wave, pure MFMA ----
  {
    const int it = w >> 2, jt = w & 3;
    const int kk2 = (it & 3) << 4;  // Kt read key: (it*16+r16)>>4 == it
    const int vk = jt << 4;
    f32x4 acc = {0.f, 0.f, 0.f, 0.f};
#pragma unroll
    for (int kk = 0; kk < 4; ++kk) {
      const int s0 = kk * 32 + g * 8;
      bf16x8 af = *(const bf16x8*)&Kt[(it * 16 + r16) * 136 + (s0 ^ kk2)];
      bf16x8 bv = *(const bf16x8*)&Vt[(jt * 16 + r16) * 136 + (s0 ^ vk)];
      acc = __builtin_amdgcn_mfma_f32_16x16x32_bf16(af, bv, acc, 0, 0, 0);
    }
#pragma unroll
    for (int r = 0; r < 4; ++r)
      chunkA[(size_t)blk * 4096 + (it * 16 + g * 4 + r) * 64 + jt * 16 + r16] =
          acc[r];
  }
}

// ---------------- Phase B: sequential carry across chunks ----------------
__global__ __launch_bounds__(256) void chunk_carry(
    const float* __restrict__ chunkA, const float* __restrict__ s0,
    const float* __restrict__ td,
    float* __restrict__ chunkS, float* __restrict__ Sout,
    int Hh, int NC, int Lc) {
  const int blk = blockIdx.x;
  const int bh = blk >> 2, q = blk & 3;
  const int h = bh % Hh;
  const int e4 = q * 1024 + threadIdx.x * 4;
  const int i = e4 >> 6;
  const float wL = expf(-(float)Lc * expf(td[h * 64 + i]));
  f32x4 S = *(const f32x4*)&s0[(size_t)bh * 4096 + e4];
  for (int c = 0; c < NC; ++c) {
    *(f32x4*)&chunkS[((size_t)bh * NC + c) * 4096 + e4] = S;
    f32x4 A = *(const f32x4*)&chunkA[((size_t)bh * NC + c) * 4096 + e4];
#pragma unroll
    for (int t = 0; t < 4; ++t) S[t] = fmaf(wL, S[t], A[t]);
  }
  *(f32x4*)&Sout[(size_t)bh * 4096 + e4] = S;
}

// ======== Phase C: inter-chunk contribution via MFMA + gnorm + gate ========
// R12-verified (107 -> ~30us).
__global__ __launch_bounds__(512) void chunk_out(
    const float* __restrict__ OattIn, const float* __restrict__ chunkS,
    const ushort_t* __restrict__ Rm, const ushort_t* __restrict__ Gm,
    const float* __restrict__ td,
    const float* __restrict__ lnw, const float* __restrict__ lnb,
    ushort_t* __restrict__ Xo, int Tt, int Hh, int NC, int Lc) {
  __shared__ ushort_t rLb[128 * 72];  // r * w^tau, bf16
  __shared__ ushort_t St[64 * 72];    // S^T: St[j][i], bf16
  __shared__ float Ob[128 * 68];      // matmul output, f32
  __shared__ float wp[16 * 68];       // w^d
  __shared__ float w16p[8 * 68];      // w^{16q}

  const int blk = blockIdx.x;
  const int bh = blk / NC, c = blk % NC;
  const int b = bh / Hh, h = bh % Hh;
  const int tid = threadIdx.x;
  const int lane = tid & 63, w = tid >> 6;   // 8 waves
  const int r16 = lane & 15, g = lane >> 4;
  const int Cc = Hh * 64;
  const size_t rowbase = (size_t)b * Tt + (size_t)c * Lc;

  // ---- (1) global loads to regs ----
  const int srow = tid >> 2;           // 0..127
  const int scol = (tid & 3) * 16;
  u16x8 r0 = *(const u16x8*)&Rm[(rowbase + srow) * Cc + h * 64 + scol];
  u16x8 r1 = *(const u16x8*)&Rm[(rowbase + srow) * Cc + h * 64 + scol + 8];
  const int jj = tid & 63, i0 = (tid >> 6) * 8;  // St: 8 elems/thread
  float sv[8];
#pragma unroll
  for (int e = 0; e < 8; ++e)
    sv[e] = chunkS[(size_t)blk * 4096 + (i0 + e) * 64 + jj];

  // ---- (2) power tables ----
  if (tid < 64) {
    const float ev = expf(td[h * 64 + tid]);
    const float wv = expf(-ev);
    float p = 1.f;
#pragma unroll
    for (int d = 0; d < 16; ++d) { wp[d * 68 + tid] = p; p *= wv; }
    float pq = 1.f;  // p == w^16
#pragma unroll
    for (int q = 0; q < 8; ++q) { w16p[q * 68 + tid] = pq; pq *= p; }
  }
  __syncthreads();

  // ---- (3) LDS: rLb = r .* w^tau (tables), St = S^T ----
  {
    const float* fa = &wp[(srow & 15) * 68 + scol];
    const float* gq = &w16p[(srow >> 4) * 68 + scol];
    u16x8 a2, b2;
#pragma unroll
    for (int e = 0; e < 8; ++e) {
      a2[e] = f2bf(bf2f(r0[e]) * (fa[e] * gq[e]));
      b2[e] = f2bf(bf2f(r1[e]) * (fa[e + 8] * gq[e + 8]));
    }
    *(u16x8*)&rLb[srow * 72 + scol] = a2;
    *(u16x8*)&rLb[srow * 72 + scol + 8] = b2;
#pragma unroll
    for (int e = 0; e < 8; ++e) St[jj * 72 + i0 + e] = f2bf(sv[e]);
  }
  __syncthreads();

  // ---- (4) MFMA: Ob = Oatt + rLb @ St^T  (wave w owns t-tile w) ----
#pragma unroll
  for (int jt = 0; jt < 4; ++jt) {
    f32x4 acc;
    const int row0 = w * 16 + g * 4;
#pragma unroll
    for (int r = 0; r < 4; ++r)
      acc[r] = OattIn[(rowbase + row0 + r) * Cc + h * 64 + jt * 16 + r16];
#pragma unroll
    for (int ks = 0; ks < 2; ++ks) {
      bf16x8 af = *(const bf16x8*)&rLb[(w * 16 + r16) * 72 + ks * 32 + g * 8];
      bf16x8 bv = *(const bf16x8*)&St[(jt * 16 + r16) * 72 + ks * 32 + g * 8];
      acc = __builtin_amdgcn_mfma_f32_16x16x32_bf16(af, bv, acc, 0, 0, 0);
    }
#pragma unroll
    for (int r = 0; r < 4; ++r)
      Ob[(row0 + r) * 68 + jt * 16 + r16] = acc[r];
  }
  __syncthreads();

  // ---- (5) groupnorm + gate (1 LDS read per element) ----
  const float lw = lnw[h * 64 + lane];
  const float lb = lnb[h * 64 + lane];
  for (int k = 0; k < 16; ++k) {
    const int tau = w + 8 * k;
    const size_t goff = (rowbase + tau) * Cc + h * 64 + lane;
    const float acc = Ob[tau * 68 + lane];
    float s = acc, s2 = acc * acc;
#pragma unroll
    for (int m = 1; m < 64; m <<= 1) {
      s += __shfl_xor(s, m);
      s2 += __shfl_xor(s2, m);
    }
    const float mean = s * (1.f / 64.f);
    const float var = s2 * (1.f / 64.f) - mean * mean;
    const float inv = 1.f / sqrtf(var + 1e-5f);
    const float y = (acc - mean) * inv * lw + lb;
    const float gv = bf2f(Gm[goff]);
    const float gate = gv / (1.f + expf(-gv));
    Xo[goff] = f2bf(y * gate);
  }
}

// ---------------- host launch ----------------
extern "C" void kernel_launch(void* const* d_in, const int* in_sizes, int n_in,
                              void* d_out, int out_size, void* d_ws, size_t ws_size,
                              hipStream_t stream) {
  const int B = 4, T = 2048, Cc = 2048, H = 32;
  const int M = B * T;
  const int NC = 16, Lc = 128;

  const float* hidden = (const float*)d_in[0];
  const float* td     = (const float*)d_in[1];
  const float* tf     = (const float*)d_in[2];
  const float* Wr     = (const float*)d_in[3];
  const float* Wk     = (const float*)d_in[4];
  const float* Wv     = (const float*)d_in[5];
  const float* Wg     = (const float*)d_in[6];
  const float* Wo     = (const float*)d_in[7];
  const float* mix_r  = (const float*)d_in[8];
  const float* mix_k  = (const float*)d_in[9];
  const float* mix_v  = (const float*)d_in[10];
  const float* mix_g  = (const float*)d_in[11];
  const float* lnw    = (const float*)d_in[12];
  const float* lnb    = (const float*)d_in[13];
  const float* s0     = (const float*)d_in[14];

  const size_t SZ_WT = (size_t)Cc * Cc * 2;  // 8 MB
  const size_t SZ_X  = (size_t)M * Cc * 2;   // 32 MB
  const size_t NEED  = 5 * SZ_WT + 6 * SZ_X; // 232 MB

  if (ws_size < NEED) return;  // clean wrong-answer instead of fault

  float* out  = (float*)d_out;                      // [M, C] (final)
  float* sfin = (float*)d_out + (size_t)M * Cc;     // [B,H,64,64] (final)
  ushort_t* xg = (ushort_t*)d_out;                  // scratch in d_out[0,32MB)
  ushort_t* gb = (ushort_t*)d_out + (size_t)M * Cc; // scratch in d_out[32,64MB)

  char* ws = (char*)d_ws;
  ushort_t* wt[5];
  for (int z = 0; z < 5; ++z) wt[z] = (ushort_t*)(ws + z * SZ_WT);
  char* regX = ws + 5 * SZ_WT;   // 96 MB
  char* regY = regX + 3 * SZ_X;  // 96 MB
  ushort_t* xr = (ushort_t*)regX;
  ushort_t* xk = (ushort_t*)(regX + SZ_X);
  ushort_t* xv = (ushort_t*)(regX + 2 * SZ_X);
  ushort_t* rb = (ushort_t*)regY;
  ushort_t* kb = (ushort_t*)(regY + SZ_X);
  ushort_t* vb = (ushort_t*)(regY + 2 * SZ_X);
  float* oatt   = (float*)regX;                 // 64 MB (over xr,xk)
  float* chunkA = (float*)(regX + 2 * SZ_X);    // 32 MB (over xv)
  float* chunkS = (float*)(regY + SZ_X);        // 32 MB (over kb)
  ushort_t* xo  = (ushort_t*)(regY + 2 * SZ_X); // 32 MB (over vb)

  {  // fused: weights transpose+cast (bid<5120) | time-shift mix (row blocks)
    PrepArgs a;
    a.W[0] = Wr; a.W[1] = Wk; a.W[2] = Wv; a.W[3] = Wg; a.W[4] = Wo;
    for (int z = 0; z < 5; ++z) a.Wt[z] = wt[z];
    a.Hd = hidden;
    a.mr = mix_r; a.mk = mix_k; a.mv = mix_v; a.mg = mix_g;
    a.xr = xr; a.xk = xk; a.xv = xv; a.xg = xg;
    prep<<<5120 + M, 256, 0, stream>>>(a, Cc, M, T);
  }

  {  // r,k,v,g = x_i @ W_i (z-batched)
    GemmArgs a;
    a.A[0] = xr; a.A[1] = xk; a.A[2] = xv; a.A[3] = xg;
    for (int z = 0; z < 4; ++z) a.Bt[z] = wt[z];
    a.C[0] = rb; a.C[1] = kb; a.C[2] = vb; a.C[3] = gb;
    dim3 g(Cc / 256, M / 256, 4);
    gemm256<1><<<g, 512, 131072, stream>>>(a, M, Cc, Cc);
  }

  wkv_chunk<<<B * H * NC, 1024, 131712, stream>>>(rb, kb, vb, td, tf, oatt,
                                                  chunkA, T, H, NC, Lc);
  chunk_carry<<<B * H * 4, 256, 0, stream>>>(chunkA, s0, td, chunkS, sfin,
                                             H, NC, Lc);
  chunk_out<<<B * H * NC, 512, 0, stream>>>(oatt, chunkS, rb, gb, td, lnw, lnb,
                                            xo, T, H, NC, Lc);

  {  // out = xo @ Wo (f32 output)
    GemmArgs a = {};
    a.A[0] = xo; a.Bt[0] = wt[4]; a.C[0] = out;
    dim3 g(Cc / 256, M / 256, 1);
    gemm256<0><<<g, 512, 131072, stream>>>(a, M, Cc, Cc);
  }
}

// Round 20
// 514.079 us; speedup vs baseline: 1.0261x; 1.0261x over previous
//
#include <hip/hip_runtime.h>
#include <stdint.h>

typedef unsigned short ushort_t;
typedef __attribute__((ext_vector_type(8))) short bf16x8;
typedef __attribute__((ext_vector_type(4))) float f32x4;
typedef __attribute__((ext_vector_type(8))) unsigned short u16x8;

__device__ __forceinline__ ushort_t f2bf(float f) {
  union { float f; unsigned u; } v; v.f = f;
  unsigned r = v.u + 0x7fffu + ((v.u >> 16) & 1u);
  return (ushort_t)(r >> 16);
}
__device__ __forceinline__ float bf2f(ushort_t u) {
  union { unsigned u; float f; } v; v.u = ((unsigned)u) << 16;
  return v.f;
}

__device__ __forceinline__ void gload_lds16(const void* g, void* l) {
  __builtin_amdgcn_global_load_lds(
      (const __attribute__((address_space(1))) void*)g,
      (__attribute__((address_space(3))) void*)l, 16, 0, 0);
}

// ---------------- fused prep: weight transpose+cast | time-shift mix -------
// R15-verified (83us; ~3.4 TB/s, structural BW limit for this pattern).
struct PrepArgs {
  const float* W[5];
  ushort_t* Wt[5];
  const float* Hd;
  const float* mr; const float* mk; const float* mv; const float* mg;
  ushort_t* xr; ushort_t* xk; ushort_t* xv; ushort_t* xg;
};

__global__ __launch_bounds__(256) void prep(PrepArgs a, int n, int Mrows, int Tt) {
  const int bid = blockIdx.x;
  const int tid = threadIdx.x;
  if (bid < 5120) {
    // ---- weight transpose+cast, 64x64 tile ----
    const int z = bid >> 10;
    const int tt = bid & 1023;
    const int bx = tt & 31, by = tt >> 5;
    const float* __restrict__ W = a.W[z];
    ushort_t* __restrict__ Wt = a.Wt[z];
    __shared__ float tile[64][65];
    const int cx = tid & 15, ry = tid >> 4;  // load: 16 col-groups x 16 rows
#pragma unroll
    for (int r = 0; r < 4; ++r) {
      const int row = ry + 16 * r;
      f32x4 v = *(const f32x4*)&W[(size_t)(by * 64 + row) * n + bx * 64 + cx * 4];
      tile[row][cx * 4 + 0] = v[0];
      tile[row][cx * 4 + 1] = v[1];
      tile[row][cx * 4 + 2] = v[2];
      tile[row][cx * 4 + 3] = v[3];
    }
    __syncthreads();
    const int gx = tid & 7, oy = tid >> 3;  // write: 8 col-groups x 32 rows
#pragma unroll
    for (int r = 0; r < 2; ++r) {
      const int orow = oy + 32 * r;
      u16x8 o;
#pragma unroll
      for (int e = 0; e < 8; ++e) o[e] = f2bf(tile[gx * 8 + e][orow]);
      *(u16x8*)&Wt[(size_t)(bx * 64 + orow) * n + by * 64 + gx * 8] = o;
    }
    return;
  }
  // ---- mix path: one block per row ----
  const int Cc = n;
  const int row = bid - 5120;  // 0..Mrows-1
  const int t = row & (Tt - 1);
  const float* __restrict__ Hd = a.Hd;
  const size_t e = (size_t)row * Cc + tid * 8;
  const int c = tid * 8;
  f32x4 h0 = *(const f32x4*)&Hd[e];
  f32x4 h1 = *(const f32x4*)&Hd[e + 4];
  f32x4 sA = {0.f, 0.f, 0.f, 0.f}, sB = {0.f, 0.f, 0.f, 0.f};
  if (t != 0) {
    sA = *(const f32x4*)&Hd[e - Cc];
    sB = *(const f32x4*)&Hd[e - Cc + 4];
  }
  f32x4 mA[4], mB[4];
  mA[0] = *(const f32x4*)&a.mr[c]; mB[0] = *(const f32x4*)&a.mr[c + 4];
  mA[1] = *(const f32x4*)&a.mk[c]; mB[1] = *(const f32x4*)&a.mk[c + 4];
  mA[2] = *(const f32x4*)&a.mv[c]; mB[2] = *(const f32x4*)&a.mv[c + 4];
  mA[3] = *(const f32x4*)&a.mg[c]; mB[3] = *(const f32x4*)&a.mg[c + 4];
  u16x8 o[4];
#pragma unroll
  for (int w = 0; w < 4; ++w) {
#pragma unroll
    for (int q = 0; q < 4; ++q) {
      o[w][q]     = f2bf(sA[q] + (h0[q] - sA[q]) * mA[w][q]);
      o[w][q + 4] = f2bf(sB[q] + (h1[q] - sB[q]) * mB[w][q]);
    }
  }
  *(u16x8*)&a.xr[e] = o[0];
  *(u16x8*)&a.xk[e] = o[1];
  *(u16x8*)&a.xv[e] = o[2];
  *(u16x8*)&a.xg[e] = o[3];
}

// ======== 256x256 bf16 GEMM, counted-vmcnt pipeline, XOR-swizzled LDS ========
// EXACT R15/R18-verified schedule (best measured: 517.4us total).  4 phases,
// m->n->ks MFMA order, 4 barriers/K-tile, vmcnt(8) never 0 in-loop, staging
// via wave-uniform base + single per-thread voffset, A-half/B-half staged
// around ph2's MFMAs.  R16 (ks-hoist), R17 (pacing-barrier removal), and
// R19 (full m201-style phase bracket) all measured <= neutral or worse ->
// this template is at its structural ceiling (~1030 TF, MfmaUtil ~45%);
// the next step up is the full m201 8-phase port (needs race-screening).
struct GemmArgs {
  const ushort_t* A[4];
  const ushort_t* Bt[4];
  void* C[4];
};

__device__ __forceinline__ void stage_mat(const ushort_t* __restrict__ base,
                                          int K, int voff, char* ldsmat,
                                          int tid) {
#pragma unroll
  for (int hf = 0; hf < 2; ++hf)
#pragma unroll
    for (int s = 0; s < 2; ++s)
      gload_lds16(base + (size_t)(hf * 128 + s * 64) * K + voff,
                  ldsmat + hf * 16384 + s * 8192 + tid * 16);
}

template <int BF16OUT>
__global__ __launch_bounds__(512, 1) void gemm256(GemmArgs args, int M, int N, int K) {
  extern __shared__ char lds[];  // 131072 bytes: 2 bufs x (A 32KB | B 32KB)
  const int z = blockIdx.z;
  const ushort_t* __restrict__ A = args.A[z];
  const ushort_t* __restrict__ Bt = args.Bt[z];

  const int tid = threadIdx.x;
  const int lane = tid & 63, w = tid >> 6;
  const int wm = w >> 2, wn = w & 3;       // 2 x 4 waves
  const int r16 = lane & 15, kb = lane >> 4;

  // XCD-aware bijective swizzle (nwg % 8 == 0 for our shapes)
  const int nbx = N >> 8;
  const int nwg = nbx * (M >> 8);
  const int orig = blockIdx.y * nbx + blockIdx.x;
  const int wid = (orig & 7) * (nwg >> 3) + (orig >> 3);
  const int bm0 = (wid / nbx) << 8;
  const int bn0 = (wid % nbx) << 8;

  // Per-thread staging source offset (elements), shared by all 8 gloads.
  const int trow = tid >> 3;  // 0..63
  const int voff = trow * K + (((((tid & 7) * 16) ^ ((trow & 7) << 4))) >> 1);
  const ushort_t* __restrict__ Abase = A + (size_t)bm0 * K;
  const ushort_t* __restrict__ Bbase = Bt + (size_t)bn0 * K;

  // Swizzled LDS byte offsets (ks=0 only; ks=1 = off ^ 64, carry-free since
  // low 7 bits of the unswizzled offset are kb*16 <= 48).
  int aoff[8], boff[4];
#pragma unroll
  for (int mi = 0; mi < 8; ++mi) {
    const int d = (mi * 16 + r16) * 128 + kb * 16;
    aoff[mi] = wm * 16384 + (d ^ (((d >> 7) & 7) << 4));
  }
#pragma unroll
  for (int ni = 0; ni < 4; ++ni) {
    const int d = ((wn & 1) * 64 + ni * 16 + r16) * 128 + kb * 16;
    boff[ni] = 32768 + (wn >> 1) * 16384 + (d ^ (((d >> 7) & 7) << 4));
  }

  f32x4 acc[8][4] = {};
  const int NT = K >> 6;

  // prologue: tiles 0,1 -> bufs 0,1; wait tile0 (8 of 16 loads), tile1 flies
  stage_mat(Abase, K, voff, lds, tid);
  stage_mat(Bbase, K, voff, lds + 32768, tid);
  stage_mat(Abase + 64, K, voff, lds + 65536, tid);
  stage_mat(Bbase + 64, K, voff, lds + 65536 + 32768, tid);
  asm volatile("s_waitcnt vmcnt(8)" ::: "memory");
  asm volatile("s_barrier" ::: "memory");

  for (int t = 0; t < NT; ++t) {
    const int cur = t & 1;
    char* cbase = lds + cur * 65536;
    bf16x8 ah[4][2], bq[4][2];

    // ---- ph0: read A-half0 + B-quad0; MFMA (mi 0-3, ni 0-1) ----
#pragma unroll
    for (int m = 0; m < 4; ++m) {
      ah[m][0] = *(const bf16x8*)(cbase + aoff[m]);
      ah[m][1] = *(const bf16x8*)(cbase + (aoff[m] ^ 64));
    }
#pragma unroll
    for (int n = 0; n < 2; ++n) {
      bq[n][0] = *(const bf16x8*)(cbase + boff[n]);
      bq[n][1] = *(const bf16x8*)(cbase + (boff[n] ^ 64));
    }
    asm volatile("s_barrier" ::: "memory");
    __builtin_amdgcn_s_setprio(1);
#pragma unroll
    for (int m = 0; m < 4; ++m)
#pragma unroll
      for (int n = 0; n < 2; ++n)
#pragma unroll
        for (int ks = 0; ks < 2; ++ks)
          acc[m][n] = __builtin_amdgcn_mfma_f32_16x16x32_bf16(
              ah[m][ks], bq[n][ks], acc[m][n], 0, 0, 0);
    __builtin_amdgcn_s_setprio(0);

    // ---- ph1: read B-quad1; MFMA (mi 0-3, ni 2-3) ----
#pragma unroll
    for (int n = 2; n < 4; ++n) {
      bq[n][0] = *(const bf16x8*)(cbase + boff[n]);
      bq[n][1] = *(const bf16x8*)(cbase + (boff[n] ^ 64));
    }
    asm volatile("s_barrier" ::: "memory");
    __builtin_amdgcn_s_setprio(1);
#pragma unroll
    for (int m = 0; m < 4; ++m)
#pragma unroll
      for (int n = 2; n < 4; ++n)
#pragma unroll
        for (int ks = 0; ks < 2; ++ks)
          acc[m][n] = __builtin_amdgcn_mfma_f32_16x16x32_bf16(
              ah[m][ks], bq[n][ks], acc[m][n], 0, 0, 0);
    __builtin_amdgcn_s_setprio(0);

    // ---- ph2: read A-half1; barrier (buf[cur] fully read); stage t+2
    //      A-half now, B-half after ph2's MFMAs (issue under compute) ----
#pragma unroll
    for (int m = 0; m < 4; ++m) {
      ah[m][0] = *(const bf16x8*)(cbase + aoff[4 + m]);
      ah[m][1] = *(const bf16x8*)(cbase + (aoff[4 + m] ^ 64));
    }
    asm volatile("s_barrier" ::: "memory");
    if (t + 2 < NT)
      stage_mat(Abase + (t + 2) * 64, K, voff, cbase, tid);
    __builtin_amdgcn_s_setprio(1);
#pragma unroll
    for (int m = 0; m < 4; ++m)
#pragma unroll
      for (int n = 0; n < 2; ++n)
#pragma unroll
        for (int ks = 0; ks < 2; ++ks)
          acc[4 + m][n] = __builtin_amdgcn_mfma_f32_16x16x32_bf16(
              ah[m][ks], bq[n][ks], acc[4 + m][n], 0, 0, 0);

    // ---- ph3: stage t+2 B-half; MFMA (mi 4-7, ni 2-3) ----
    if (t + 2 < NT)
      stage_mat(Bbase + (t + 2) * 64, K, voff, cbase + 32768, tid);
#pragma unroll
    for (int m = 0; m < 4; ++m)
#pragma unroll
      for (int n = 2; n < 4; ++n)
#pragma unroll
        for (int ks = 0; ks < 2; ++ks)
          acc[4 + m][n] = __builtin_amdgcn_mfma_f32_16x16x32_bf16(
              ah[m][ks], bq[n][ks], acc[4 + m][n], 0, 0, 0);
    __builtin_amdgcn_s_setprio(0);

    // ---- boundary: t+1 must have landed in buf[cur^1]; t+2 keeps flying ----
    if (t + 1 < NT) {
      if (t + 2 < NT)
        asm volatile("s_waitcnt vmcnt(8)" ::: "memory");  // drain t+1 only
      else
        asm volatile("s_waitcnt vmcnt(0)" ::: "memory");  // tail drain
      asm volatile("s_barrier" ::: "memory");
    }
  }

  const int row0 = bm0 + wm * 128 + kb * 4;
  const int col0 = bn0 + wn * 64 + r16;
#pragma unroll
  for (int mi = 0; mi < 8; ++mi)
#pragma unroll
    for (int ni = 0; ni < 4; ++ni) {
      f32x4 v = acc[mi][ni];
      const int row = row0 + mi * 16;
      const int col = col0 + ni * 16;
#pragma unroll
      for (int rr = 0; rr < 4; ++rr) {
        if (BF16OUT)
          ((ushort_t*)args.C[z])[(size_t)(row + rr) * N + col] = f2bf(v[rr]);
        else
          ((float*)args.C[z])[(size_t)(row + rr) * N + col] = v[rr];
      }
    }
}

// ======== Phase A: intra-chunk WKV via chunked-matmul (MFMA) ========
// R14-verified: 1024 threads / 16 waves, swizzled Vt/Kt, power tables.
__global__ __launch_bounds__(1024, 1) void wkv_chunk(
    const ushort_t* __restrict__ Rm, const ushort_t* __restrict__ Km,
    const ushort_t* __restrict__ Vm, const float* __restrict__ td,
    const float* __restrict__ tf,
    float* __restrict__ Oatt, float* __restrict__ chunkA,
    int Tt, int Hh, int NC, int Lc) {
  extern __shared__ char smem[];
  ushort_t* Rs  = (ushort_t*)(smem + 0);       // [128][72] raw r
  ushort_t* Ks  = (ushort_t*)(smem + 18432);   // [128][72] raw k (diag only)
  ushort_t* Ks2 = (ushort_t*)(smem + 36864);   // [128][72] k*w^{15-s16}
  ushort_t* Vt  = (ushort_t*)(smem + 55296);   // [64][136] v transp (swizzled)
  ushort_t* Kt  = (ushort_t*)(smem + 72704);   // [64][136] k*w^{127-s} (swz)
  ushort_t* At  = (ushort_t*)(smem + 90112);   // [128][136]
  float* wp   = (float*)(smem + 124928);       // [16][68] w^d
  float* w16p = (float*)(smem + 129280);       // [8][68]  w^{16q}
  float* u_   = (float*)(smem + 131456);       // [64]

  const int blk = blockIdx.x;
  const int bh = blk / NC, c = blk % NC;
  const int b = bh / Hh, h = bh % Hh;
  const int tid = threadIdx.x;
  const int lane = tid & 63, w = tid >> 6;       // 16 waves
  const int r16 = lane & 15, g = lane >> 4;      // frag coords
  const int Cc = Hh * 64;
  const size_t base = ((size_t)b * Tt + (size_t)c * Lc) * Cc + h * 64;

  // ---- (1) global loads to registers (latency hides under table fill) ----
  const int srow = tid >> 3;            // 0..127
  const int scol = (tid & 7) * 8;       // 0,8,...,56
  const size_t gb = base + (size_t)srow * Cc + scol;
  u16x8 r0 = *(const u16x8*)&Rm[gb];
  u16x8 k0 = *(const u16x8*)&Km[gb];
  u16x8 v0 = *(const u16x8*)&Vm[gb];

  // ---- (2) power tables ----
  if (tid < 64) {
    const float ev = expf(td[h * 64 + tid]);
    const float wv = expf(-ev);
    u_[tid] = tf[h * 64 + tid];
    float p = 1.f;
#pragma unroll
    for (int d = 0; d < 16; ++d) { wp[d * 68 + tid] = p; p *= wv; }
    float pq = 1.f;  // p == w^16 now
#pragma unroll
    for (int q = 0; q < 8; ++q) { w16p[q * 68 + tid] = pq; pq *= p; }
  }
  __syncthreads();

  // ---- (3) LDS writes (raw + pre-scaled) + zero At ----
  {
    *(u16x8*)&Rs[srow * 72 + scol] = r0;
    *(u16x8*)&Ks[srow * 72 + scol] = k0;
    const int s16 = srow & 15, shi = srow >> 4;
    const float* fa = &wp[(15 - s16) * 68 + scol];   // w^{15-s16}[i]
    const float* gq = &w16p[(7 - shi) * 68 + scol];  // w^{16(7-shi)}[i]
    u16x8 a2;
#pragma unroll
    for (int e = 0; e < 8; ++e) a2[e] = f2bf(bf2f(k0[e]) * fa[e]);
    *(u16x8*)&Ks2[srow * 72 + scol] = a2;
    // Vt/Kt channel-row keyed swizzle: col' = srow ^ key.  key uniform per
    // instruction: (scol+e)>>4 == scol>>4 for e<8 (scol multiple of 8).
    const int key = ((scol >> 4) & 3) << 4;
    const int sc = srow ^ key;
#pragma unroll
    for (int e = 0; e < 8; ++e) {
      Vt[(scol + e) * 136 + sc] = v0[e];
      Kt[(scol + e) * 136 + sc] = f2bf(bf2f(k0[e]) * fa[e] * gq[e]);
    }
    const u16x8 z = {};
    for (int o = tid; o < (128 * 136) / 8; o += 1024) *(u16x8*)&At[o * 8] = z;
  }
  __syncthreads();

  // ---- Phase A: 28 off-diagonal tiles via MFMA (no exp2f) ----
  for (int p = w; p < 28; p += 16) {
    int tau = 1, cum = 0;
    while (cum + tau <= p) { cum += tau; ++tau; }
    const int sig = p - cum;
    const float* wr  = &wp[r16 * 68];                 // w^{t16}[i]
    const float* w16 = &w16p[(tau - sig - 1) * 68];   // w^{16(dcls-1)}[i]
    f32x4 acc = {0.f, 0.f, 0.f, 0.f};
#pragma unroll
    for (int ks = 0; ks < 2; ++ks) {
      const int ib = ks * 32 + g * 8;
      u16x8 rv = *(const u16x8*)&Rs[(tau * 16 + r16) * 72 + ib];
      bf16x8 kv = *(const bf16x8*)&Ks2[(sig * 16 + r16) * 72 + ib];
      f32x4 wa = *(const f32x4*)&wr[ib];
      f32x4 wb = *(const f32x4*)&wr[ib + 4];
      f32x4 sa = *(const f32x4*)&w16[ib];
      f32x4 sb = *(const f32x4*)&w16[ib + 4];
      union { bf16x8 v; ushort_t s[8]; } af;
#pragma unroll
      for (int e = 0; e < 4; ++e) {
        af.s[e]     = f2bf(bf2f(rv[e]) * (wa[e] * sa[e]));
        af.s[e + 4] = f2bf(bf2f(rv[e + 4]) * (wb[e] * sb[e]));
      }
      acc = __builtin_amdgcn_mfma_f32_16x16x32_bf16(af.v, kv, acc, 0, 0, 0);
    }
#pragma unroll
    for (int r = 0; r < 4; ++r)
      At[(tau * 16 + g * 4 + r) * 136 + sig * 16 + r16] = f2bf(acc[r]);
  }

  // ---- Phase B: 8 diagonal tiles entry-wise (raw Rs/Ks, unchanged) ----
  for (int rr = 0; rr < 2; ++rr) {
    const int eid = tid + rr * 1024;
    if (eid >= 1088) break;
    const int tile = eid / 136;
    const int e2 = eid % 136;
    int t = 0, cum = 0;
    while (cum + t + 1 <= e2) { cum += t + 1; ++t; }
    const int s = e2 - cum;
    const ushort_t* rrow = &Rs[(tile * 16 + t) * 72];
    const ushort_t* krow = &Ks[(tile * 16 + s) * 72];
    const float* frow = (s < t) ? &wp[(t - s - 1) * 68] : u_;
    float acc = 0.f;
#pragma unroll
    for (int i0 = 0; i0 < 64; i0 += 8) {
      u16x8 rv = *(const u16x8*)&rrow[i0];
      u16x8 kv = *(const u16x8*)&krow[i0];
      f32x4 f0 = *(const f32x4*)&frow[i0];
      f32x4 f1 = *(const f32x4*)&frow[i0 + 4];
#pragma unroll
      for (int e = 0; e < 4; ++e) {
        acc = fmaf(bf2f(rv[e]), bf2f(kv[e]) * f0[e], acc);
        acc = fmaf(bf2f(rv[e + 4]), bf2f(kv[e + 4]) * f1[e], acc);
      }
    }
    At[(tile * 16 + t) * 136 + tile * 16 + s] = f2bf(acc);
  }
  __syncthreads();

  // ---- Phase C: out = A @ V, balanced: wave w -> units {w, 31-w}
  //      (unit u: tt = u>>2, jt = u&3); 5 MFMA per wave ----
#pragma unroll
  for (int half = 0; half < 2; ++half) {
    const int u = half ? (31 - w) : w;
    const int tt = u >> 2, jt = u & 3;
    const int nk = (tt + 2) >> 1;  // ceil((tt+1)/2) k-steps of 32
    const int vk = jt << 4;        // Vt read key: (jt*16+r16)>>4 == jt
    f32x4 acc = {0.f, 0.f, 0.f, 0.f};
    for (int kk = 0; kk < nk; ++kk) {
      bf16x8 af = *(const bf16x8*)&At[(tt * 16 + r16) * 136 + kk * 32 + g * 8];
      bf16x8 bv = *(const bf16x8*)&Vt[(jt * 16 + r16) * 136 +
                                      ((kk * 32 + g * 8) ^ vk)];
      acc = __builtin_amdgcn_mfma_f32_16x16x32_bf16(af, bv, acc, 0, 0, 0);
    }
#pragma unroll
    for (int r = 0; r < 4; ++r)
      Oatt[base + (size_t)(tt * 16 + g * 4 + r) * Cc + jt * 16 + r16] = acc[r];
  }

  // ---- Phase D: chunkA = Kt(pre-scaled) @ V -- 1 tile/wave, pure MFMA ----
  {
    const int it = w >> 2, jt = w & 3;
    const int kk2 = (it & 3) << 4;  // Kt read key: (it*16+r16)>>4 == it
    const int vk = jt << 4;
    f32x4 acc = {0.f, 0.f, 0.f, 0.f};
#pragma unroll
    for (int kk = 0; kk < 4; ++kk) {
      const int s0 = kk * 32 + g * 8;
      bf16x8 af = *(const bf16x8*)&Kt[(it * 16 + r16) * 136 + (s0 ^ kk2)];
      bf16x8 bv = *(const bf16x8*)&Vt[(jt * 16 + r16) * 136 + (s0 ^ vk)];
      acc = __builtin_amdgcn_mfma_f32_16x16x32_bf16(af, bv, acc, 0, 0, 0);
    }
#pragma unroll
    for (int r = 0; r < 4; ++r)
      chunkA[(size_t)blk * 4096 + (it * 16 + g * 4 + r) * 64 + jt * 16 + r16] =
          acc[r];
  }
}

// ---------------- Phase B: sequential carry across chunks ----------------
__global__ __launch_bounds__(256) void chunk_carry(
    const float* __restrict__ chunkA, const float* __restrict__ s0,
    const float* __restrict__ td,
    float* __restrict__ chunkS, float* __restrict__ Sout,
    int Hh, int NC, int Lc) {
  const int blk = blockIdx.x;
  const int bh = blk >> 2, q = blk & 3;
  const int h = bh % Hh;
  const int e4 = q * 1024 + threadIdx.x * 4;
  const int i = e4 >> 6;
  const float wL = expf(-(float)Lc * expf(td[h * 64 + i]));
  f32x4 S = *(const f32x4*)&s0[(size_t)bh * 4096 + e4];
  for (int c = 0; c < NC; ++c) {
    *(f32x4*)&chunkS[((size_t)bh * NC + c) * 4096 + e4] = S;
    f32x4 A = *(const f32x4*)&chunkA[((size_t)bh * NC + c) * 4096 + e4];
#pragma unroll
    for (int t = 0; t < 4; ++t) S[t] = fmaf(wL, S[t], A[t]);
  }
  *(f32x4*)&Sout[(size_t)bh * 4096 + e4] = S;
}

// ======== Phase C: inter-chunk contribution via MFMA + gnorm + gate ========
// R12-verified (107 -> ~30us).
__global__ __launch_bounds__(512) void chunk_out(
    const float* __restrict__ OattIn, const float* __restrict__ chunkS,
    const ushort_t* __restrict__ Rm, const ushort_t* __restrict__ Gm,
    const float* __restrict__ td,
    const float* __restrict__ lnw, const float* __restrict__ lnb,
    ushort_t* __restrict__ Xo, int Tt, int Hh, int NC, int Lc) {
  __shared__ ushort_t rLb[128 * 72];  // r * w^tau, bf16
  __shared__ ushort_t St[64 * 72];    // S^T: St[j][i], bf16
  __shared__ float Ob[128 * 68];      // matmul output, f32
  __shared__ float wp[16 * 68];       // w^d
  __shared__ float w16p[8 * 68];      // w^{16q}

  const int blk = blockIdx.x;
  const int bh = blk / NC, c = blk % NC;
  const int b = bh / Hh, h = bh % Hh;
  const int tid = threadIdx.x;
  const int lane = tid & 63, w = tid >> 6;   // 8 waves
  const int r16 = lane & 15, g = lane >> 4;
  const int Cc = Hh * 64;
  const size_t rowbase = (size_t)b * Tt + (size_t)c * Lc;

  // ---- (1) global loads to regs ----
  const int srow = tid >> 2;           // 0..127
  const int scol = (tid & 3) * 16;
  u16x8 r0 = *(const u16x8*)&Rm[(rowbase + srow) * Cc + h * 64 + scol];
  u16x8 r1 = *(const u16x8*)&Rm[(rowbase + srow) * Cc + h * 64 + scol + 8];
  const int jj = tid & 63, i0 = (tid >> 6) * 8;  // St: 8 elems/thread
  float sv[8];
#pragma unroll
  for (int e = 0; e < 8; ++e)
    sv[e] = chunkS[(size_t)blk * 4096 + (i0 + e) * 64 + jj];

  // ---- (2) power tables ----
  if (tid < 64) {
    const float ev = expf(td[h * 64 + tid]);
    const float wv = expf(-ev);
    float p = 1.f;
#pragma unroll
    for (int d = 0; d < 16; ++d) { wp[d * 68 + tid] = p; p *= wv; }
    float pq = 1.f;  // p == w^16
#pragma unroll
    for (int q = 0; q < 8; ++q) { w16p[q * 68 + tid] = pq; pq *= p; }
  }
  __syncthreads();

  // ---- (3) LDS: rLb = r .* w^tau (tables), St = S^T ----
  {
    const float* fa = &wp[(srow & 15) * 68 + scol];
    const float* gq = &w16p[(srow >> 4) * 68 + scol];
    u16x8 a2, b2;
#pragma unroll
    for (int e = 0; e < 8; ++e) {
      a2[e] = f2bf(bf2f(r0[e]) * (fa[e] * gq[e]));
      b2[e] = f2bf(bf2f(r1[e]) * (fa[e + 8] * gq[e + 8]));
    }
    *(u16x8*)&rLb[srow * 72 + scol] = a2;
    *(u16x8*)&rLb[srow * 72 + scol + 8] = b2;
#pragma unroll
    for (int e = 0; e < 8; ++e) St[jj * 72 + i0 + e] = f2bf(sv[e]);
  }
  __syncthreads();

  // ---- (4) MFMA: Ob = Oatt + rLb @ St^T  (wave w owns t-tile w) ----
#pragma unroll
  for (int jt = 0; jt < 4; ++jt) {
    f32x4 acc;
    const int row0 = w * 16 + g * 4;
#pragma unroll
    for (int r = 0; r < 4; ++r)
      acc[r] = OattIn[(rowbase + row0 + r) * Cc + h * 64 + jt * 16 + r16];
#pragma unroll
    for (int ks = 0; ks < 2; ++ks) {
      bf16x8 af = *(const bf16x8*)&rLb[(w * 16 + r16) * 72 + ks * 32 + g * 8];
      bf16x8 bv = *(const bf16x8*)&St[(jt * 16 + r16) * 72 + ks * 32 + g * 8];
      acc = __builtin_amdgcn_mfma_f32_16x16x32_bf16(af, bv, acc, 0, 0, 0);
    }
#pragma unroll
    for (int r = 0; r < 4; ++r)
      Ob[(row0 + r) * 68 + jt * 16 + r16] = acc[r];
  }
  __syncthreads();

  // ---- (5) groupnorm + gate (1 LDS read per element) ----
  const float lw = lnw[h * 64 + lane];
  const float lb = lnb[h * 64 + lane];
  for (int k = 0; k < 16; ++k) {
    const int tau = w + 8 * k;
    const size_t goff = (rowbase + tau) * Cc + h * 64 + lane;
    const float acc = Ob[tau * 68 + lane];
    float s = acc, s2 = acc * acc;
#pragma unroll
    for (int m = 1; m < 64; m <<= 1) {
      s += __shfl_xor(s, m);
      s2 += __shfl_xor(s2, m);
    }
    const float mean = s * (1.f / 64.f);
    const float var = s2 * (1.f / 64.f) - mean * mean;
    const float inv = 1.f / sqrtf(var + 1e-5f);
    const float y = (acc - mean) * inv * lw + lb;
    const float gv = bf2f(Gm[goff]);
    const float gate = gv / (1.f + expf(-gv));
    Xo[goff] = f2bf(y * gate);
  }
}

// ---------------- host launch ----------------
extern "C" void kernel_launch(void* const* d_in, const int* in_sizes, int n_in,
                              void* d_out, int out_size, void* d_ws, size_t ws_size,
                              hipStream_t stream) {
  const int B = 4, T = 2048, Cc = 2048, H = 32;
  const int M = B * T;
  const int NC = 16, Lc = 128;

  const float* hidden = (const float*)d_in[0];
  const float* td     = (const float*)d_in[1];
  const float* tf     = (const float*)d_in[2];
  const float* Wr     = (const float*)d_in[3];
  const float* Wk     = (const float*)d_in[4];
  const float* Wv     = (const float*)d_in[5];
  const float* Wg     = (const float*)d_in[6];
  const float* Wo     = (const float*)d_in[7];
  const float* mix_r  = (const float*)d_in[8];
  const float* mix_k  = (const float*)d_in[9];
  const float* mix_v  = (const float*)d_in[10];
  const float* mix_g  = (const float*)d_in[11];
  const float* lnw    = (const float*)d_in[12];
  const float* lnb    = (const float*)d_in[13];
  const float* s0     = (const float*)d_in[14];

  const size_t SZ_WT = (size_t)Cc * Cc * 2;  // 8 MB
  const size_t SZ_X  = (size_t)M * Cc * 2;   // 32 MB
  const size_t NEED  = 5 * SZ_WT + 6 * SZ_X; // 232 MB

  if (ws_size < NEED) return;  // clean wrong-answer instead of fault

  float* out  = (float*)d_out;                      // [M, C] (final)
  float* sfin = (float*)d_out + (size_t)M * Cc;     // [B,H,64,64] (final)
  ushort_t* xg = (ushort_t*)d_out;                  // scratch in d_out[0,32MB)
  ushort_t* gb = (ushort_t*)d_out + (size_t)M * Cc; // scratch in d_out[32,64MB)

  char* ws = (char*)d_ws;
  ushort_t* wt[5];
  for (int z = 0; z < 5; ++z) wt[z] = (ushort_t*)(ws + z * SZ_WT);
  char* regX = ws + 5 * SZ_WT;   // 96 MB
  char* regY = regX + 3 * SZ_X;  // 96 MB
  ushort_t* xr = (ushort_t*)regX;
  ushort_t* xk = (ushort_t*)(regX + SZ_X);
  ushort_t* xv = (ushort_t*)(regX + 2 * SZ_X);
  ushort_t* rb = (ushort_t*)regY;
  ushort_t* kb = (ushort_t*)(regY + SZ_X);
  ushort_t* vb = (ushort_t*)(regY + 2 * SZ_X);
  float* oatt   = (float*)regX;                 // 64 MB (over xr,xk)
  float* chunkA = (float*)(regX + 2 * SZ_X);    // 32 MB (over xv)
  float* chunkS = (float*)(regY + SZ_X);        // 32 MB (over kb)
  ushort_t* xo  = (ushort_t*)(regY + 2 * SZ_X); // 32 MB (over vb)

  {  // fused: weights transpose+cast (bid<5120) | time-shift mix (row blocks)
    PrepArgs a;
    a.W[0] = Wr; a.W[1] = Wk; a.W[2] = Wv; a.W[3] = Wg; a.W[4] = Wo;
    for (int z = 0; z < 5; ++z) a.Wt[z] = wt[z];
    a.Hd = hidden;
    a.mr = mix_r; a.mk = mix_k; a.mv = mix_v; a.mg = mix_g;
    a.xr = xr; a.xk = xk; a.xv = xv; a.xg = xg;
    prep<<<5120 + M, 256, 0, stream>>>(a, Cc, M, T);
  }

  {  // r,k,v,g = x_i @ W_i (z-batched)
    GemmArgs a;
    a.A[0] = xr; a.A[1] = xk; a.A[2] = xv; a.A[3] = xg;
    for (int z = 0; z < 4; ++z) a.Bt[z] = wt[z];
    a.C[0] = rb; a.C[1] = kb; a.C[2] = vb; a.C[3] = gb;
    dim3 g(Cc / 256, M / 256, 4);
    gemm256<1><<<g, 512, 131072, stream>>>(a, M, Cc, Cc);
  }

  wkv_chunk<<<B * H * NC, 1024, 131712, stream>>>(rb, kb, vb, td, tf, oatt,
                                                  chunkA, T, H, NC, Lc);
  chunk_carry<<<B * H * 4, 256, 0, stream>>>(chunkA, s0, td, chunkS, sfin,
                                             H, NC, Lc);
  chunk_out<<<B * H * NC, 512, 0, stream>>>(oatt, chunkS, rb, gb, td, lnw, lnb,
                                            xo, T, H, NC, Lc);

  {  // out = xo @ Wo (f32 output)
    GemmArgs a = {};
    a.A[0] = xo; a.Bt[0] = wt[4]; a.C[0] = out;
    dim3 g(Cc / 256, M / 256, 1);
    gemm256<0><<<g, 512, 131072, stream>>>(a, M, Cc, Cc);
  }
}